// Round 4
// baseline (211.765 us; speedup 1.0000x reference)
//
#include <hip/hip_runtime.h>
#include <hip/hip_bf16.h>
#include <math.h>

typedef unsigned short u16;
typedef unsigned int u32;
typedef __attribute__((ext_vector_type(8))) short short8;
typedef __attribute__((ext_vector_type(8))) unsigned short ushort8;
typedef __attribute__((ext_vector_type(4))) float floatx4;
typedef __attribute__((ext_vector_type(16))) float floatx16;

#define CDIM   1024
#define TSEQ   2048
#define NHEAD  16
#define HDIM   64

// -1/(80*ln2): exp(-dist/80) = exp2(dist * C2)
#define C2_CONST  (-0.01803368801111874f)
#define M2C2_CONST (0.03606737602223748f)

static __device__ __forceinline__ u16 f2bf(float f) {
    u32 u = __float_as_uint(f);
    u += 0x7fffu + ((u >> 16) & 1u);   // RNE
    return (u16)(u >> 16);
}

// packed f32x2 -> bf16x2 (RNE), single VOP3
static __device__ __forceinline__ u32 cvtpk(float a, float b) {
    u32 r;
    asm("v_cvt_pk_bf16_f32 %0, %1, %2" : "=v"(r) : "v"(a), "v"(b));
    return r;
}

// fast tanh: 1 - 2/(exp2(2x*log2e)+1)
static __device__ __forceinline__ float ftanh(float x) {
    float e = exp2f(x * 2.88539008f);
    float r = __builtin_amdgcn_rcpf(e + 1.0f);
    return fmaf(-2.0f, r, 1.0f);
}

// async global->LDS, 16 bytes per lane
static __device__ __forceinline__ void gll16(const void* g, void* l) {
    __builtin_amdgcn_global_load_lds(
        (const __attribute__((address_space(1))) unsigned int*)g,
        (__attribute__((address_space(3))) unsigned int*)l, 16, 0, 0);
}

// ---------------------------------------------------------------------------
// prep: bid<4096 -> xa=tanh(x)+xsq ; else W mats (tanh+wsq for q/k/v, copy Wo)
__global__ __launch_bounds__(256) void prep(const float* __restrict__ x,
                                            const float* __restrict__ Wq, const float* __restrict__ Wk,
                                            const float* __restrict__ Wv, const float* __restrict__ Wo,
                                            u16* __restrict__ xa,
                                            u16* __restrict__ waq, u16* __restrict__ wak,
                                            u16* __restrict__ wav, u16* __restrict__ wob,
                                            float* __restrict__ xsq,
                                            float* __restrict__ sqq, float* __restrict__ sqk,
                                            float* __restrict__ sqv) {
    __shared__ float red[4];
    int bid = blockIdx.x, tid = threadIdx.x;
    const float* src; u16* dst; float* sq; int row; bool do_tanh = true;
    if (bid < 4096) {
        row = bid; src = x; dst = xa; sq = xsq;
    } else {
        int mat = (bid - 4096) >> 10; row = (bid - 4096) & 1023;
        src = (mat == 0) ? Wq : (mat == 1) ? Wk : (mat == 2) ? Wv : Wo;
        dst = (mat == 0) ? waq : (mat == 1) ? wak : (mat == 2) ? wav : wob;
        sq  = (mat == 0) ? sqq : (mat == 1) ? sqk : (mat == 2) ? sqv : nullptr;
        do_tanh = (mat < 3);
    }
    float4 v = reinterpret_cast<const float4*>(src + (size_t)row * CDIM)[tid];
    if (do_tanh) {
        float a0 = ftanh(v.x), a1 = ftanh(v.y), a2 = ftanh(v.z), a3 = ftanh(v.w);
        *reinterpret_cast<ushort4*>(dst + (size_t)row * CDIM + tid * 4) =
            make_ushort4(f2bf(a0), f2bf(a1), f2bf(a2), f2bf(a3));
        float s = a0*a0 + a1*a1 + a2*a2 + a3*a3;
        #pragma unroll
        for (int m = 1; m < 64; m <<= 1) s += __shfl_xor(s, m, 64);
        if ((tid & 63) == 0) red[tid >> 6] = s;
        __syncthreads();
        if (tid == 0 && sq) sq[row] = red[0] + red[1] + red[2] + red[3];
    } else {
        *reinterpret_cast<ushort4*>(dst + (size_t)row * CDIM + tid * 4) =
            make_ushort4(f2bf(v.x), f2bf(v.y), f2bf(v.z), f2bf(v.w));
    }
}

// ---------------------------------------------------------------------------
// Fused QKV GEMM: C = A * Bm^T, distance epilogue; z = 0(q)/1(k)/2(v).
// 128x128 tile, BK=64, global_load_lds(16B), 4-bit XOR swizzle.
// k epilogue computes per-head row sq * C2 -> ksC2T (q-side sq not needed:
// it cancels in softmax).
__global__ __launch_bounds__(256) void gemm_qkv(const u16* __restrict__ xa,
                                                const u16* __restrict__ waq, const u16* __restrict__ wak, const u16* __restrict__ wav,
                                                u16* __restrict__ qb, u16* __restrict__ kb, u16* __restrict__ vT,
                                                const float* __restrict__ xsq,
                                                const float* __restrict__ sqq, const float* __restrict__ sqk, const float* __restrict__ sqv,
                                                const float* __restrict__ gq, const float* __restrict__ gk, const float* __restrict__ gv,
                                                float* __restrict__ ksC2T) {
    __shared__ __align__(16) u16 As[128 * 64];
    __shared__ __align__(16) u16 Bs[128 * 64];
    int z = blockIdx.z;
    const u16* Bm     = (z == 0) ? waq : (z == 1) ? wak : wav;
    const float* wsq  = (z == 0) ? sqq : (z == 1) ? sqk : sqv;
    const float* gain = (z == 0) ? gq : (z == 1) ? gk : gv;

    int tid = threadIdx.x;
    int m0 = blockIdx.y * 128, n0 = blockIdx.x * 128;
    int w = tid >> 6, l = tid & 63, wm = w >> 1, wn = w & 1, g = l >> 4, c = l & 15;
    int r8 = l >> 3, sl7 = l & 7;
    int cmask = (c & 7) ^ (c >> 3);

    floatx4 acc[4][4] = {};

    for (int kt = 0; kt < 16; ++kt) {
        __syncthreads();
        #pragma unroll
        for (int i = 0; i < 4; i++) {
            int ch = w * 4 + i;
            int row = ch * 8 + r8;
            int sl = sl7 ^ r8 ^ (ch & 1);
            gll16(xa + (size_t)(m0 + row) * CDIM + kt * 64 + sl * 8, &As[ch * 512 + l * 8]);
            gll16(Bm + (size_t)(n0 + row) * CDIM + kt * 64 + sl * 8, &Bs[ch * 512 + l * 8]);
        }
        __syncthreads();
        short8 af[2][4], bf[2][4];
        #pragma unroll
        for (int kk = 0; kk < 2; kk++) {
            #pragma unroll
            for (int mi = 0; mi < 4; mi++)
                af[kk][mi] = *reinterpret_cast<const short8*>(
                    &As[(wm * 64 + mi * 16 + c) * 64 + (((kk * 4 + g) ^ cmask) << 3)]);
            #pragma unroll
            for (int ni = 0; ni < 4; ni++)
                bf[kk][ni] = *reinterpret_cast<const short8*>(
                    &Bs[(wn * 64 + ni * 16 + c) * 64 + (((kk * 4 + g) ^ cmask) << 3)]);
        }
        #pragma unroll
        for (int kk = 0; kk < 2; kk++)
            #pragma unroll
            for (int mi = 0; mi < 4; mi++)
                #pragma unroll
                for (int ni = 0; ni < 4; ni++)
                    acc[mi][ni] = __builtin_amdgcn_mfma_f32_16x16x32_bf16(af[kk][mi], bf[kk][ni], acc[mi][ni], 0, 0, 0);
    }

    if (z < 2) {
        u16* outH = (z == 0) ? qb : kb;
        float part[4][4] = {};
        #pragma unroll
        for (int mi = 0; mi < 4; mi++) {
            int rowb = m0 + wm * 64 + mi * 16 + g * 4;
            #pragma unroll
            for (int ni = 0; ni < 4; ni++) {
                int col = n0 + wn * 64 + ni * 16 + c;
                float wsqc = wsq[col], gn = gain[col];
                #pragma unroll
                for (int r = 0; r < 4; r++) {
                    float l2 = fmaxf(xsq[rowb + r] + wsqc - 2.f * acc[mi][ni][r], 0.f);
                    float th = ftanh((0.5f - l2 * (1.f / 1024.f)) * gn);
                    outH[(size_t)(rowb + r) * CDIM + col] = f2bf(th);
                    part[mi][r] += th * th;
                }
            }
        }
        if (z == 1) {   // only k needs the per-head row-norm (pre-scaled by C2)
            int hh = blockIdx.x * 2 + wn;
            #pragma unroll
            for (int mi = 0; mi < 4; mi++)
                #pragma unroll
                for (int r = 0; r < 4; r++) {
                    float s = part[mi][r];
                    s += __shfl_xor(s, 1, 64); s += __shfl_xor(s, 2, 64);
                    s += __shfl_xor(s, 4, 64); s += __shfl_xor(s, 8, 64);
                    if (c == 0) {
                        int row = m0 + wm * 64 + mi * 16 + g * 4 + r;
                        int bb = row >> 11, t = row & 2047;
                        ksC2T[(size_t)(bb * NHEAD + hh) * TSEQ + t] = s * C2_CONST;
                    }
                }
        }
    } else {  // v: store transposed per head vT[b][h][d][t]
        #pragma unroll
        for (int mi = 0; mi < 4; mi++) {
            int rowb = m0 + wm * 64 + mi * 16 + g * 4;
            #pragma unroll
            for (int ni = 0; ni < 4; ni++) {
                int col = n0 + wn * 64 + ni * 16 + c;
                float wsqc = wsq[col], gn = gain[col];
                float vals[4];
                #pragma unroll
                for (int r = 0; r < 4; r++) {
                    float l2 = fmaxf(xsq[rowb + r] + wsqc - 2.f * acc[mi][ni][r], 0.f);
                    vals[r] = (0.5f - l2 * (1.f / 1024.f)) * gn;
                }
                int bb = rowb >> 11, t0 = rowb & 2047;
                int hh = col >> 6, dd = col & 63;
                ushort4 pv = make_ushort4(f2bf(vals[0]), f2bf(vals[1]), f2bf(vals[2]), f2bf(vals[3]));
                *reinterpret_cast<ushort4*>(&vT[(((size_t)(bb * NHEAD + hh) * HDIM + dd) << 11) + t0]) = pv;
            }
        }
    }
}

// ---------------------------------------------------------------------------
// Final GEMM: out = ao * Wo^T, f32 store.
__global__ __launch_bounds__(256) void gemm_out(const u16* __restrict__ A, const u16* __restrict__ Bm,
                                                float* __restrict__ outF) {
    __shared__ __align__(16) u16 As[128 * 64];
    __shared__ __align__(16) u16 Bs[128 * 64];
    int tid = threadIdx.x;
    int m0 = blockIdx.y * 128, n0 = blockIdx.x * 128;
    int w = tid >> 6, l = tid & 63, wm = w >> 1, wn = w & 1, g = l >> 4, c = l & 15;
    int r8 = l >> 3, sl7 = l & 7;
    int cmask = (c & 7) ^ (c >> 3);

    floatx4 acc[4][4] = {};

    for (int kt = 0; kt < 16; ++kt) {
        __syncthreads();
        #pragma unroll
        for (int i = 0; i < 4; i++) {
            int ch = w * 4 + i;
            int row = ch * 8 + r8;
            int sl = sl7 ^ r8 ^ (ch & 1);
            gll16(A + (size_t)(m0 + row) * CDIM + kt * 64 + sl * 8, &As[ch * 512 + l * 8]);
            gll16(Bm + (size_t)(n0 + row) * CDIM + kt * 64 + sl * 8, &Bs[ch * 512 + l * 8]);
        }
        __syncthreads();
        short8 af[2][4], bf[2][4];
        #pragma unroll
        for (int kk = 0; kk < 2; kk++) {
            #pragma unroll
            for (int mi = 0; mi < 4; mi++)
                af[kk][mi] = *reinterpret_cast<const short8*>(
                    &As[(wm * 64 + mi * 16 + c) * 64 + (((kk * 4 + g) ^ cmask) << 3)]);
            #pragma unroll
            for (int ni = 0; ni < 4; ni++)
                bf[kk][ni] = *reinterpret_cast<const short8*>(
                    &Bs[(wn * 64 + ni * 16 + c) * 64 + (((kk * 4 + g) ^ cmask) << 3)]);
        }
        #pragma unroll
        for (int kk = 0; kk < 2; kk++)
            #pragma unroll
            for (int mi = 0; mi < 4; mi++)
                #pragma unroll
                for (int ni = 0; ni < 4; ni++)
                    acc[mi][ni] = __builtin_amdgcn_mfma_f32_16x16x32_bf16(af[kk][mi], bf[kk][ni], acc[mi][ni], 0, 0, 0);
    }

    #pragma unroll
    for (int mi = 0; mi < 4; mi++) {
        int rowb = m0 + wm * 64 + mi * 16 + g * 4;
        #pragma unroll
        for (int ni = 0; ni < 4; ni++) {
            int col = n0 + wn * 64 + ni * 16 + c;
            #pragma unroll
            for (int r = 0; r < 4; r++)
                outF[(size_t)(rowb + r) * CDIM + col] = acc[mi][ni][r];
        }
    }
}

// ---------------------------------------------------------------------------
// attn4: 32x32x16 MFMA, swapped QK^T (lane owns one t-column), fixed-m softmax,
// in-register P->A rebuild (cvt_pk + shfl_xor(32) + cndmask) -- no P LDS bounce.
// grid (16, 16, 2) x 256; 4 waves x 32 q-rows; 32 s-tiles of 64.
__global__ __launch_bounds__(256) void attn4(const u16* __restrict__ q, const u16* __restrict__ k,
                                             const u16* __restrict__ vT,
                                             const float* __restrict__ ksC2T, u16* __restrict__ ao) {
    int tt = blockIdx.x, h = blockIdx.y, b = blockIdx.z;
    int tid = threadIdx.x, w = tid >> 6, l = tid & 63;
    int hi = l >> 5, t32 = l & 31;
    int twb = tt * 128 + w * 32;

    __shared__ __align__(16) u16 Ks[2][64 * 64];   // [s][d-slots], XOR-swizzled
    __shared__ __align__(16) u16 Vs[2][64 * 64];   // [d][s-slots], XOR-swizzled
    __shared__ __align__(16) float Ls[4][32];

    // Q B-fragments: B[k=d][col=t], lane: Q[t=t32][d = ks*16 + hi*8 + j]
    short8 qf[4];
    size_t qrow = (size_t)(b * TSEQ + twb + t32) * CDIM + h * HDIM;
    #pragma unroll
    for (int ks = 0; ks < 4; ks++)
        qf[ks] = *reinterpret_cast<const short8*>(&q[qrow + ks * 16 + hi * 8]);

    const float* ksb = ksC2T + (size_t)(b * NHEAD + h) * TSEQ;
    const u16* kbase = k + (size_t)(b * TSEQ) * CDIM + h * HDIM;
    const u16* vbase = vT + (size_t)(b * NHEAD + h) * HDIM * TSEQ;

    int r8 = l >> 3, sl7 = l & 7;
    int lmask = (l & 7) ^ ((l >> 3) & 1);

    floatx16 oacc[2] = {};
    float lrun = 0.f;

    // prologue: stage tile 0
    #pragma unroll
    for (int i = 0; i < 2; i++) {
        int ch = w * 2 + i;
        int sl = sl7 ^ r8 ^ (ch & 1);
        gll16(kbase + (size_t)(ch * 8 + r8) * CDIM + sl * 8, &Ks[0][ch * 512 + l * 8]);
        gll16(vbase + (size_t)(ch * 8 + r8) * TSEQ + sl * 8, &Vs[0][ch * 512 + l * 8]);
    }
    __syncthreads();

    for (int st = 0; st < 32; ++st) {
        int cur = st & 1;
        if (st < 31) {
            int s1 = (st + 1) * 64;
            #pragma unroll
            for (int i = 0; i < 2; i++) {
                int ch = w * 2 + i;
                int sl = sl7 ^ r8 ^ (ch & 1);
                gll16(kbase + (size_t)(s1 + ch * 8 + r8) * CDIM + sl * 8, &Ks[cur ^ 1][ch * 512 + l * 8]);
                gll16(vbase + (size_t)(ch * 8 + r8) * TSEQ + s1 + sl * 8, &Vs[cur ^ 1][ch * 512 + l * 8]);
            }
        }

        // ---- S^T = K.Q^T per 32-s-tile; softmax in-register; pack to bf16
        u32 pk[2][8];
        #pragma unroll
        for (int stile = 0; stile < 2; ++stile) {
            short8 kf[4];
            #pragma unroll
            for (int kstep = 0; kstep < 4; kstep++) {
                int row = stile * 32 + t32;
                int slot = (kstep * 2 + hi) ^ lmask;
                kf[kstep] = *reinterpret_cast<const short8*>(&Ks[cur][row * 64 + slot * 8]);
            }
            floatx16 sxx = {};
            #pragma unroll
            for (int kstep = 0; kstep < 4; kstep++)
                sxx = __builtin_amdgcn_mfma_f32_32x32x16_bf16(kf[kstep], qf[kstep], sxx, 0, 0, 0);

            float p[16];
            #pragma unroll
            for (int qq = 0; qq < 4; qq++) {
                float4 kc = *reinterpret_cast<const float4*>(
                    &ksb[st * 64 + stile * 32 + qq * 8 + hi * 4]);
                float ka[4] = {kc.x, kc.y, kc.z, kc.w};
                #pragma unroll
                for (int j = 0; j < 4; j++) {
                    float arg = fmaf(sxx[qq * 4 + j], M2C2_CONST, ka[j]);
                    float pv = exp2f(arg);
                    p[qq * 4 + j] = pv;
                    lrun += pv;
                }
            }
            #pragma unroll
            for (int i = 0; i < 8; i++)
                pk[stile][i] = cvtpk(p[2 * i], p[2 * i + 1]);
        }

        // ---- cross-half exchange: each half sends what the other needs
        u32 ex[2][4];
        #pragma unroll
        for (int stile = 0; stile < 2; ++stile) {
            #pragma unroll
            for (int m = 0; m < 4; m++) {
                const int p0a[4] = {0, 1, 4, 5};
                u32 send = hi ? pk[stile][p0a[m]] : pk[stile][p0a[m] + 2];
                ex[stile][m] = (u32)__shfl_xor((int)send, 32, 64);
            }
        }

        // ---- O += P.V  (A-frag built in-register)
        #pragma unroll
        for (int ks = 0; ks < 4; ks++) {
            int e = ks & 1, stl = ks >> 1;
            union { u32 u[4]; short8 s; } au;
            au.u[0] = hi ? ex[stl][2 * e]     : pk[stl][4 * e];
            au.u[1] = hi ? ex[stl][2 * e + 1] : pk[stl][4 * e + 1];
            au.u[2] = hi ? pk[stl][4 * e + 2] : ex[stl][2 * e];
            au.u[3] = hi ? pk[stl][4 * e + 3] : ex[stl][2 * e + 1];
            short8 af = au.s;
            #pragma unroll
            for (int dt = 0; dt < 2; dt++) {
                int row = dt * 32 + t32;
                int slot = (ks * 2 + hi) ^ lmask;
                short8 vf = *reinterpret_cast<const short8*>(&Vs[cur][row * 64 + slot * 8]);
                oacc[dt] = __builtin_amdgcn_mfma_f32_32x32x16_bf16(af, vf, oacc[dt], 0, 0, 0);
            }
        }

        __syncthreads();   // all waves done with cur; next tile drained
    }

    // ---- epilogue: l broadcast (t-indexed -> row-indexed) + normalize
    float ltot = lrun + __shfl_xor(lrun, 32, 64);
    if (l < 32) Ls[w][l] = ltot;
    float4 lv[4];
    #pragma unroll
    for (int qq = 0; qq < 4; qq++)
        lv[qq] = *reinterpret_cast<const float4*>(&Ls[w][qq * 8 + hi * 4]);
    #pragma unroll
    for (int dt = 0; dt < 2; dt++)
        #pragma unroll
        for (int r = 0; r < 16; ++r) {
            int trow = (r & 3) + 8 * (r >> 2) + 4 * hi;
            float lval = (r & 3) == 0 ? lv[r >> 2].x : (r & 3) == 1 ? lv[r >> 2].y
                       : (r & 3) == 2 ? lv[r >> 2].z : lv[r >> 2].w;
            ao[(size_t)(b * TSEQ + twb + trow) * CDIM + h * HDIM + dt * 32 + t32] =
                f2bf(oacc[dt][r] * __builtin_amdgcn_rcpf(lval));
        }
}

// ---------------------------------------------------------------------------
extern "C" void kernel_launch(void* const* d_in, const int* in_sizes, int n_in,
                              void* d_out, int out_size, void* d_ws, size_t ws_size,
                              hipStream_t stream) {
    const float* x  = (const float*)d_in[0];
    const float* Wq = (const float*)d_in[1];
    const float* gq = (const float*)d_in[2];
    const float* Wk = (const float*)d_in[3];
    const float* gk = (const float*)d_in[4];
    const float* Wv = (const float*)d_in[5];
    const float* gv = (const float*)d_in[6];
    const float* Wo = (const float*)d_in[7];
    float* out = (float*)d_out;

    char* p = (char*)d_ws;
    u16* xa  = (u16*)p;  p += (size_t)8 << 20;
    u16* qb  = (u16*)p;  p += (size_t)8 << 20;
    u16* kb  = (u16*)p;  p += (size_t)8 << 20;
    u16* vT  = (u16*)p;  p += (size_t)8 << 20;
    u16* ao  = (u16*)p;  p += (size_t)8 << 20;
    u16* waq = (u16*)p;  p += (size_t)2 << 20;
    u16* wak = (u16*)p;  p += (size_t)2 << 20;
    u16* wav = (u16*)p;  p += (size_t)2 << 20;
    u16* wob = (u16*)p;  p += (size_t)2 << 20;
    float* xsq   = (float*)p; p += 4096 * 4;
    float* sqq   = (float*)p; p += 1024 * 4;
    float* sqk   = (float*)p; p += 1024 * 4;
    float* sqv   = (float*)p; p += 1024 * 4;
    float* ksC2T = (float*)p; p += 4096 * 16 * 4;
    (void)ws_size; (void)in_sizes; (void)n_in; (void)out_size;

    prep<<<8192, 256, 0, stream>>>(x, Wq, Wk, Wv, Wo, xa, waq, wak, wav, wob,
                                   xsq, sqq, sqk, sqv);

    dim3 gqkv(8, 32, 3);
    gemm_qkv<<<gqkv, 256, 0, stream>>>(xa, waq, wak, wav, qb, kb, vT, xsq,
                                       sqq, sqk, sqv, gq, gk, gv, ksC2T);

    dim3 ga(16, NHEAD, 2);
    attn4<<<ga, 256, 0, stream>>>(qb, kb, vT, ksC2T, ao);

    dim3 gg(8, 32);
    gemm_out<<<gg, 256, 0, stream>>>(ao, wob, out);
}

// Round 5
// 211.617 us; speedup vs baseline: 1.0007x; 1.0007x over previous
//
#include <hip/hip_runtime.h>
#include <hip/hip_bf16.h>
#include <math.h>

typedef unsigned short u16;
typedef unsigned int u32;
typedef __attribute__((ext_vector_type(8))) short short8;
typedef __attribute__((ext_vector_type(8))) unsigned short ushort8;
typedef __attribute__((ext_vector_type(4))) float floatx4;
typedef __attribute__((ext_vector_type(16))) float floatx16;
typedef __attribute__((ext_vector_type(4))) u32 uint4v;

#define CDIM   1024
#define TSEQ   2048
#define NHEAD  16
#define HDIM   64

// -1/(80*ln2): exp(-dist/80) = exp2(dist * C2)
#define C2_CONST  (-0.01803368801111874f)
#define M2C2_CONST (0.03606737602223748f)

static __device__ __forceinline__ u16 f2bf(float f) {
    u32 u = __float_as_uint(f);
    u += 0x7fffu + ((u >> 16) & 1u);   // RNE
    return (u16)(u >> 16);
}

// packed f32x2 -> bf16x2 (RNE), single VOP3
static __device__ __forceinline__ u32 cvtpk(float a, float b) {
    u32 r;
    asm("v_cvt_pk_bf16_f32 %0, %1, %2" : "=v"(r) : "v"(a), "v"(b));
    return r;
}

// fast tanh: 1 - 2/(exp2(2x*log2e)+1)
static __device__ __forceinline__ float ftanh(float x) {
    float e = exp2f(x * 2.88539008f);
    float r = __builtin_amdgcn_rcpf(e + 1.0f);
    return fmaf(-2.0f, r, 1.0f);
}

// async global->LDS, 16 bytes per lane
static __device__ __forceinline__ void gll16(const void* g, void* l) {
    __builtin_amdgcn_global_load_lds(
        (const __attribute__((address_space(1))) unsigned int*)g,
        (__attribute__((address_space(3))) unsigned int*)l, 16, 0, 0);
}

// ---------------------------------------------------------------------------
// prep: bid<4096 -> xa=tanh(x)+xsq ; else W mats (tanh+wsq for q/k/v, copy Wo)
__global__ __launch_bounds__(256) void prep(const float* __restrict__ x,
                                            const float* __restrict__ Wq, const float* __restrict__ Wk,
                                            const float* __restrict__ Wv, const float* __restrict__ Wo,
                                            u16* __restrict__ xa,
                                            u16* __restrict__ waq, u16* __restrict__ wak,
                                            u16* __restrict__ wav, u16* __restrict__ wob,
                                            float* __restrict__ xsq,
                                            float* __restrict__ sqq, float* __restrict__ sqk,
                                            float* __restrict__ sqv) {
    __shared__ float red[4];
    int bid = blockIdx.x, tid = threadIdx.x;
    const float* src; u16* dst; float* sq; int row; bool do_tanh = true;
    if (bid < 4096) {
        row = bid; src = x; dst = xa; sq = xsq;
    } else {
        int mat = (bid - 4096) >> 10; row = (bid - 4096) & 1023;
        src = (mat == 0) ? Wq : (mat == 1) ? Wk : (mat == 2) ? Wv : Wo;
        dst = (mat == 0) ? waq : (mat == 1) ? wak : (mat == 2) ? wav : wob;
        sq  = (mat == 0) ? sqq : (mat == 1) ? sqk : (mat == 2) ? sqv : nullptr;
        do_tanh = (mat < 3);
    }
    float4 v = reinterpret_cast<const float4*>(src + (size_t)row * CDIM)[tid];
    if (do_tanh) {
        float a0 = ftanh(v.x), a1 = ftanh(v.y), a2 = ftanh(v.z), a3 = ftanh(v.w);
        *reinterpret_cast<ushort4*>(dst + (size_t)row * CDIM + tid * 4) =
            make_ushort4(f2bf(a0), f2bf(a1), f2bf(a2), f2bf(a3));
        float s = a0*a0 + a1*a1 + a2*a2 + a3*a3;
        #pragma unroll
        for (int m = 1; m < 64; m <<= 1) s += __shfl_xor(s, m, 64);
        if ((tid & 63) == 0) red[tid >> 6] = s;
        __syncthreads();
        if (tid == 0 && sq) sq[row] = red[0] + red[1] + red[2] + red[3];
    } else {
        *reinterpret_cast<ushort4*>(dst + (size_t)row * CDIM + tid * 4) =
            make_ushort4(f2bf(v.x), f2bf(v.y), f2bf(v.z), f2bf(v.w));
    }
}

// ---------------------------------------------------------------------------
// Fused QKV GEMM: C = A * Bm^T, distance epilogue; z = 0(q)/1(k)/2(v).
// 128x128 tile, BK=64, global_load_lds(16B), 4-bit XOR swizzle.
// k epilogue computes per-head row sq * C2 -> ksC2T.
__global__ __launch_bounds__(256) void gemm_qkv(const u16* __restrict__ xa,
                                                const u16* __restrict__ waq, const u16* __restrict__ wak, const u16* __restrict__ wav,
                                                u16* __restrict__ qb, u16* __restrict__ kb, u16* __restrict__ vT,
                                                const float* __restrict__ xsq,
                                                const float* __restrict__ sqq, const float* __restrict__ sqk, const float* __restrict__ sqv,
                                                const float* __restrict__ gq, const float* __restrict__ gk, const float* __restrict__ gv,
                                                float* __restrict__ ksC2T) {
    __shared__ __align__(16) u16 As[128 * 64];
    __shared__ __align__(16) u16 Bs[128 * 64];
    int z = blockIdx.z;
    const u16* Bm     = (z == 0) ? waq : (z == 1) ? wak : wav;
    const float* wsq  = (z == 0) ? sqq : (z == 1) ? sqk : sqv;
    const float* gain = (z == 0) ? gq : (z == 1) ? gk : gv;

    int tid = threadIdx.x;
    int m0 = blockIdx.y * 128, n0 = blockIdx.x * 128;
    int w = tid >> 6, l = tid & 63, wm = w >> 1, wn = w & 1, g = l >> 4, c = l & 15;
    int r8 = l >> 3, sl7 = l & 7;
    int cmask = (c & 7) ^ (c >> 3);

    floatx4 acc[4][4] = {};

    for (int kt = 0; kt < 16; ++kt) {
        __syncthreads();
        #pragma unroll
        for (int i = 0; i < 4; i++) {
            int ch = w * 4 + i;
            int row = ch * 8 + r8;
            int sl = sl7 ^ r8 ^ (ch & 1);
            gll16(xa + (size_t)(m0 + row) * CDIM + kt * 64 + sl * 8, &As[ch * 512 + l * 8]);
            gll16(Bm + (size_t)(n0 + row) * CDIM + kt * 64 + sl * 8, &Bs[ch * 512 + l * 8]);
        }
        __syncthreads();
        short8 af[2][4], bf[2][4];
        #pragma unroll
        for (int kk = 0; kk < 2; kk++) {
            #pragma unroll
            for (int mi = 0; mi < 4; mi++)
                af[kk][mi] = *reinterpret_cast<const short8*>(
                    &As[(wm * 64 + mi * 16 + c) * 64 + (((kk * 4 + g) ^ cmask) << 3)]);
            #pragma unroll
            for (int ni = 0; ni < 4; ni++)
                bf[kk][ni] = *reinterpret_cast<const short8*>(
                    &Bs[(wn * 64 + ni * 16 + c) * 64 + (((kk * 4 + g) ^ cmask) << 3)]);
        }
        #pragma unroll
        for (int kk = 0; kk < 2; kk++)
            #pragma unroll
            for (int mi = 0; mi < 4; mi++)
                #pragma unroll
                for (int ni = 0; ni < 4; ni++)
                    acc[mi][ni] = __builtin_amdgcn_mfma_f32_16x16x32_bf16(af[kk][mi], bf[kk][ni], acc[mi][ni], 0, 0, 0);
    }

    if (z < 2) {
        u16* outH = (z == 0) ? qb : kb;
        float part[4][4] = {};
        #pragma unroll
        for (int mi = 0; mi < 4; mi++) {
            int rowb = m0 + wm * 64 + mi * 16 + g * 4;
            #pragma unroll
            for (int ni = 0; ni < 4; ni++) {
                int col = n0 + wn * 64 + ni * 16 + c;
                float wsqc = wsq[col], gn = gain[col];
                #pragma unroll
                for (int r = 0; r < 4; r++) {
                    float l2 = fmaxf(xsq[rowb + r] + wsqc - 2.f * acc[mi][ni][r], 0.f);
                    float th = ftanh((0.5f - l2 * (1.f / 1024.f)) * gn);
                    outH[(size_t)(rowb + r) * CDIM + col] = f2bf(th);
                    part[mi][r] += th * th;
                }
            }
        }
        if (z == 1) {   // only k needs the per-head row-norm (pre-scaled by C2)
            int hh = blockIdx.x * 2 + wn;
            #pragma unroll
            for (int mi = 0; mi < 4; mi++)
                #pragma unroll
                for (int r = 0; r < 4; r++) {
                    float s = part[mi][r];
                    s += __shfl_xor(s, 1, 64); s += __shfl_xor(s, 2, 64);
                    s += __shfl_xor(s, 4, 64); s += __shfl_xor(s, 8, 64);
                    if (c == 0) {
                        int row = m0 + wm * 64 + mi * 16 + g * 4 + r;
                        int bb = row >> 11, t = row & 2047;
                        ksC2T[(size_t)(bb * NHEAD + hh) * TSEQ + t] = s * C2_CONST;
                    }
                }
        }
    } else {  // v: store transposed per head vT[b][h][d][t]
        #pragma unroll
        for (int mi = 0; mi < 4; mi++) {
            int rowb = m0 + wm * 64 + mi * 16 + g * 4;
            #pragma unroll
            for (int ni = 0; ni < 4; ni++) {
                int col = n0 + wn * 64 + ni * 16 + c;
                float wsqc = wsq[col], gn = gain[col];
                float vals[4];
                #pragma unroll
                for (int r = 0; r < 4; r++) {
                    float l2 = fmaxf(xsq[rowb + r] + wsqc - 2.f * acc[mi][ni][r], 0.f);
                    vals[r] = (0.5f - l2 * (1.f / 1024.f)) * gn;
                }
                int bb = rowb >> 11, t0 = rowb & 2047;
                int hh = col >> 6, dd = col & 63;
                ushort4 pv = make_ushort4(f2bf(vals[0]), f2bf(vals[1]), f2bf(vals[2]), f2bf(vals[3]));
                *reinterpret_cast<ushort4*>(&vT[(((size_t)(bb * NHEAD + hh) * HDIM + dd) << 11) + t0]) = pv;
            }
        }
    }
}

// ---------------------------------------------------------------------------
// Final GEMM: out = ao * Wo^T, f32 store.
__global__ __launch_bounds__(256) void gemm_out(const u16* __restrict__ A, const u16* __restrict__ Bm,
                                                float* __restrict__ outF) {
    __shared__ __align__(16) u16 As[128 * 64];
    __shared__ __align__(16) u16 Bs[128 * 64];
    int tid = threadIdx.x;
    int m0 = blockIdx.y * 128, n0 = blockIdx.x * 128;
    int w = tid >> 6, l = tid & 63, wm = w >> 1, wn = w & 1, g = l >> 4, c = l & 15;
    int r8 = l >> 3, sl7 = l & 7;
    int cmask = (c & 7) ^ (c >> 3);

    floatx4 acc[4][4] = {};

    for (int kt = 0; kt < 16; ++kt) {
        __syncthreads();
        #pragma unroll
        for (int i = 0; i < 4; i++) {
            int ch = w * 4 + i;
            int row = ch * 8 + r8;
            int sl = sl7 ^ r8 ^ (ch & 1);
            gll16(A + (size_t)(m0 + row) * CDIM + kt * 64 + sl * 8, &As[ch * 512 + l * 8]);
            gll16(Bm + (size_t)(n0 + row) * CDIM + kt * 64 + sl * 8, &Bs[ch * 512 + l * 8]);
        }
        __syncthreads();
        short8 af[2][4], bf[2][4];
        #pragma unroll
        for (int kk = 0; kk < 2; kk++) {
            #pragma unroll
            for (int mi = 0; mi < 4; mi++)
                af[kk][mi] = *reinterpret_cast<const short8*>(
                    &As[(wm * 64 + mi * 16 + c) * 64 + (((kk * 4 + g) ^ cmask) << 3)]);
            #pragma unroll
            for (int ni = 0; ni < 4; ni++)
                bf[kk][ni] = *reinterpret_cast<const short8*>(
                    &Bs[(wn * 64 + ni * 16 + c) * 64 + (((kk * 4 + g) ^ cmask) << 3)]);
        }
        #pragma unroll
        for (int kk = 0; kk < 2; kk++)
            #pragma unroll
            for (int mi = 0; mi < 4; mi++)
                #pragma unroll
                for (int ni = 0; ni < 4; ni++)
                    acc[mi][ni] = __builtin_amdgcn_mfma_f32_16x16x32_bf16(af[kk][mi], bf[kk][ni], acc[mi][ni], 0, 0, 0);
    }

    #pragma unroll
    for (int mi = 0; mi < 4; mi++) {
        int rowb = m0 + wm * 64 + mi * 16 + g * 4;
        #pragma unroll
        for (int ni = 0; ni < 4; ni++) {
            int col = n0 + wn * 64 + ni * 16 + c;
            #pragma unroll
            for (int r = 0; r < 4; r++)
                outF[(size_t)(rowb + r) * CDIM + col] = acc[mi][ni][r];
        }
    }
}

// ---------------------------------------------------------------------------
// attn5: 32x32x16 MFMA, swapped QK^T, fixed-m softmax, in-register P->A rebuild
// via value-typed uint4v + bit_cast (NO union -> no scratch).
// grid (16, 16, 2) x 256; 4 waves x 32 q-rows; 32 s-tiles of 64.
__global__ __launch_bounds__(256) void attn5(const u16* __restrict__ q, const u16* __restrict__ k,
                                             const u16* __restrict__ vT,
                                             const float* __restrict__ ksC2T, u16* __restrict__ ao) {
    int tt = blockIdx.x, h = blockIdx.y, b = blockIdx.z;
    int tid = threadIdx.x, w = tid >> 6, l = tid & 63;
    int hi = l >> 5, t32 = l & 31;
    int twb = tt * 128 + w * 32;

    __shared__ __align__(16) u16 Ks[2][64 * 64];   // [s][d-slots], XOR-swizzled
    __shared__ __align__(16) u16 Vs[2][64 * 64];   // [d][s-slots], XOR-swizzled
    __shared__ __align__(16) float Ls[4][32];

    // Q B-fragments: B[k=d][col=t], lane: Q[t=t32][d = ks*16 + hi*8 + j]
    short8 qf[4];
    size_t qrow = (size_t)(b * TSEQ + twb + t32) * CDIM + h * HDIM;
    #pragma unroll
    for (int ks = 0; ks < 4; ks++)
        qf[ks] = *reinterpret_cast<const short8*>(&q[qrow + ks * 16 + hi * 8]);

    const float* ksb = ksC2T + (size_t)(b * NHEAD + h) * TSEQ;
    const u16* kbase = k + (size_t)(b * TSEQ) * CDIM + h * HDIM;
    const u16* vbase = vT + (size_t)(b * NHEAD + h) * HDIM * TSEQ;

    int r8 = l >> 3, sl7 = l & 7;
    int lmask = (l & 7) ^ ((l >> 3) & 1);

    floatx16 oacc[2] = {};
    float lrun = 0.f;

    // prologue: stage tile 0
    #pragma unroll
    for (int i = 0; i < 2; i++) {
        int ch = w * 2 + i;
        int sl = sl7 ^ r8 ^ (ch & 1);
        gll16(kbase + (size_t)(ch * 8 + r8) * CDIM + sl * 8, &Ks[0][ch * 512 + l * 8]);
        gll16(vbase + (size_t)(ch * 8 + r8) * TSEQ + sl * 8, &Vs[0][ch * 512 + l * 8]);
    }
    __syncthreads();

    for (int st = 0; st < 32; ++st) {
        int cur = st & 1;
        if (st < 31) {
            int s1 = (st + 1) * 64;
            #pragma unroll
            for (int i = 0; i < 2; i++) {
                int ch = w * 2 + i;
                int sl = sl7 ^ r8 ^ (ch & 1);
                gll16(kbase + (size_t)(s1 + ch * 8 + r8) * CDIM + sl * 8, &Ks[cur ^ 1][ch * 512 + l * 8]);
                gll16(vbase + (size_t)(ch * 8 + r8) * TSEQ + s1 + sl * 8, &Vs[cur ^ 1][ch * 512 + l * 8]);
            }
        }

        // ---- S^T = K.Q^T per 32-s-tile; softmax in-register; pack to bf16
        u32 pk[2][8];
        #pragma unroll
        for (int stile = 0; stile < 2; ++stile) {
            short8 kf[4];
            #pragma unroll
            for (int kstep = 0; kstep < 4; kstep++) {
                int row = stile * 32 + t32;
                int slot = (kstep * 2 + hi) ^ lmask;
                kf[kstep] = *reinterpret_cast<const short8*>(&Ks[cur][row * 64 + slot * 8]);
            }
            floatx16 sxx = {};
            #pragma unroll
            for (int kstep = 0; kstep < 4; kstep++)
                sxx = __builtin_amdgcn_mfma_f32_32x32x16_bf16(kf[kstep], qf[kstep], sxx, 0, 0, 0);

            float p[16];
            #pragma unroll
            for (int qq = 0; qq < 4; qq++) {
                float4 kc = *reinterpret_cast<const float4*>(
                    &ksb[st * 64 + stile * 32 + qq * 8 + hi * 4]);
                float ka[4] = {kc.x, kc.y, kc.z, kc.w};
                #pragma unroll
                for (int j = 0; j < 4; j++) {
                    float arg = fmaf(sxx[qq * 4 + j], M2C2_CONST, ka[j]);
                    float pv = exp2f(arg);
                    p[qq * 4 + j] = pv;
                    lrun += pv;
                }
            }
            #pragma unroll
            for (int i = 0; i < 8; i++)
                pk[stile][i] = cvtpk(p[2 * i], p[2 * i + 1]);
        }

        // ---- cross-half exchange: each half sends what the other needs
        u32 ex[2][4];
        #pragma unroll
        for (int stile = 0; stile < 2; ++stile) {
            #pragma unroll
            for (int m = 0; m < 4; m++) {
                const int p0a[4] = {0, 1, 4, 5};
                u32 send = hi ? pk[stile][p0a[m]] : pk[stile][p0a[m] + 2];
                ex[stile][m] = (u32)__shfl_xor((int)send, 32, 64);
            }
        }

        // ---- O += P.V  (A-frag built in-register, value-typed: no scratch)
        #pragma unroll
        for (int ks = 0; ks < 4; ks++) {
            int e = ks & 1, stl = ks >> 1;
            uint4v au;
            au.x = hi ? ex[stl][2 * e]     : pk[stl][4 * e];
            au.y = hi ? ex[stl][2 * e + 1] : pk[stl][4 * e + 1];
            au.z = hi ? pk[stl][4 * e + 2] : ex[stl][2 * e];
            au.w = hi ? pk[stl][4 * e + 3] : ex[stl][2 * e + 1];
            short8 af = __builtin_bit_cast(short8, au);
            #pragma unroll
            for (int dt = 0; dt < 2; dt++) {
                int row = dt * 32 + t32;
                int slot = (ks * 2 + hi) ^ lmask;
                short8 vf = *reinterpret_cast<const short8*>(&Vs[cur][row * 64 + slot * 8]);
                oacc[dt] = __builtin_amdgcn_mfma_f32_32x32x16_bf16(af, vf, oacc[dt], 0, 0, 0);
            }
        }

        __syncthreads();   // all waves done with cur; next tile drained
    }

    // ---- epilogue: l broadcast (t-indexed -> row-indexed) + normalize
    float ltot = lrun + __shfl_xor(lrun, 32, 64);
    if (l < 32) Ls[w][l] = ltot;
    float4 lv[4];
    #pragma unroll
    for (int qq = 0; qq < 4; qq++)
        lv[qq] = *reinterpret_cast<const float4*>(&Ls[w][qq * 8 + hi * 4]);
    #pragma unroll
    for (int dt = 0; dt < 2; dt++)
        #pragma unroll
        for (int r = 0; r < 16; ++r) {
            int trow = (r & 3) + 8 * (r >> 2) + 4 * hi;
            float lval = (r & 3) == 0 ? lv[r >> 2].x : (r & 3) == 1 ? lv[r >> 2].y
                       : (r & 3) == 2 ? lv[r >> 2].z : lv[r >> 2].w;
            ao[(size_t)(b * TSEQ + twb + trow) * CDIM + h * HDIM + dt * 32 + t32] =
                f2bf(oacc[dt][r] * __builtin_amdgcn_rcpf(lval));
        }
}

// ---------------------------------------------------------------------------
extern "C" void kernel_launch(void* const* d_in, const int* in_sizes, int n_in,
                              void* d_out, int out_size, void* d_ws, size_t ws_size,
                              hipStream_t stream) {
    const float* x  = (const float*)d_in[0];
    const float* Wq = (const float*)d_in[1];
    const float* gq = (const float*)d_in[2];
    const float* Wk = (const float*)d_in[3];
    const float* gk = (const float*)d_in[4];
    const float* Wv = (const float*)d_in[5];
    const float* gv = (const float*)d_in[6];
    const float* Wo = (const float*)d_in[7];
    float* out = (float*)d_out;

    char* p = (char*)d_ws;
    u16* xa  = (u16*)p;  p += (size_t)8 << 20;
    u16* qb  = (u16*)p;  p += (size_t)8 << 20;
    u16* kb  = (u16*)p;  p += (size_t)8 << 20;
    u16* vT  = (u16*)p;  p += (size_t)8 << 20;
    u16* ao  = (u16*)p;  p += (size_t)8 << 20;
    u16* waq = (u16*)p;  p += (size_t)2 << 20;
    u16* wak = (u16*)p;  p += (size_t)2 << 20;
    u16* wav = (u16*)p;  p += (size_t)2 << 20;
    u16* wob = (u16*)p;  p += (size_t)2 << 20;
    float* xsq   = (float*)p; p += 4096 * 4;
    float* sqq   = (float*)p; p += 1024 * 4;
    float* sqk   = (float*)p; p += 1024 * 4;
    float* sqv   = (float*)p; p += 1024 * 4;
    float* ksC2T = (float*)p; p += 4096 * 16 * 4;
    (void)ws_size; (void)in_sizes; (void)n_in; (void)out_size;

    prep<<<8192, 256, 0, stream>>>(x, Wq, Wk, Wv, Wo, xa, waq, wak, wav, wob,
                                   xsq, sqq, sqk, sqv);

    dim3 gqkv(8, 32, 3);
    gemm_qkv<<<gqkv, 256, 0, stream>>>(xa, waq, wak, wav, qb, kb, vT, xsq,
                                       sqq, sqk, sqv, gq, gk, gv, ksC2T);

    dim3 ga(16, NHEAD, 2);
    attn5<<<ga, 256, 0, stream>>>(qb, kb, vT, ksC2T, ao);

    dim3 gg(8, 32);
    gemm_out<<<gg, 256, 0, stream>>>(ao, wob, out);
}

// Round 6
// 162.356 us; speedup vs baseline: 1.3043x; 1.3034x over previous
//
#include <hip/hip_runtime.h>
#include <hip/hip_bf16.h>
#include <math.h>

typedef unsigned short u16;
typedef unsigned int u32;
typedef __attribute__((ext_vector_type(8))) short short8;
typedef __attribute__((ext_vector_type(8))) unsigned short ushort8;
typedef __attribute__((ext_vector_type(4))) float floatx4;
typedef __attribute__((ext_vector_type(16))) float floatx16;
typedef __attribute__((ext_vector_type(4))) u32 uint4v;

#define CDIM   1024
#define TSEQ   2048
#define NHEAD  16
#define HDIM   64

// -1/(80*ln2): exp(-dist/80) = exp2(dist * C2)
#define C2_CONST  (-0.01803368801111874f)
#define M2C2_CONST (0.03606737602223748f)

static __device__ __forceinline__ u16 f2bf(float f) {
    u32 u = __float_as_uint(f);
    u += 0x7fffu + ((u >> 16) & 1u);   // RNE
    return (u16)(u >> 16);
}

// packed f32x2 -> bf16x2 (RNE), single VOP3
static __device__ __forceinline__ u32 cvtpk(float a, float b) {
    u32 r;
    asm("v_cvt_pk_bf16_f32 %0, %1, %2" : "=v"(r) : "v"(a), "v"(b));
    return r;
}

// fast tanh: 1 - 2/(exp2(2x*log2e)+1)
static __device__ __forceinline__ float ftanh(float x) {
    float e = exp2f(x * 2.88539008f);
    float r = __builtin_amdgcn_rcpf(e + 1.0f);
    return fmaf(-2.0f, r, 1.0f);
}

// async global->LDS, 16 bytes per lane
static __device__ __forceinline__ void gll16(const void* g, void* l) {
    __builtin_amdgcn_global_load_lds(
        (const __attribute__((address_space(1))) unsigned int*)g,
        (__attribute__((address_space(3))) unsigned int*)l, 16, 0, 0);
}

// ---------------------------------------------------------------------------
// prep: bid<4096 -> xa=tanh(x)+xsq ; else W mats (tanh+wsq for q/k/v, copy Wo)
__global__ __launch_bounds__(256) void prep(const float* __restrict__ x,
                                            const float* __restrict__ Wq, const float* __restrict__ Wk,
                                            const float* __restrict__ Wv, const float* __restrict__ Wo,
                                            u16* __restrict__ xa,
                                            u16* __restrict__ waq, u16* __restrict__ wak,
                                            u16* __restrict__ wav, u16* __restrict__ wob,
                                            float* __restrict__ xsq,
                                            float* __restrict__ sqq, float* __restrict__ sqk,
                                            float* __restrict__ sqv) {
    __shared__ float red[4];
    int bid = blockIdx.x, tid = threadIdx.x;
    const float* src; u16* dst; float* sq; int row; bool do_tanh = true;
    if (bid < 4096) {
        row = bid; src = x; dst = xa; sq = xsq;
    } else {
        int mat = (bid - 4096) >> 10; row = (bid - 4096) & 1023;
        src = (mat == 0) ? Wq : (mat == 1) ? Wk : (mat == 2) ? Wv : Wo;
        dst = (mat == 0) ? waq : (mat == 1) ? wak : (mat == 2) ? wav : wob;
        sq  = (mat == 0) ? sqq : (mat == 1) ? sqk : (mat == 2) ? sqv : nullptr;
        do_tanh = (mat < 3);
    }
    float4 v = reinterpret_cast<const float4*>(src + (size_t)row * CDIM)[tid];
    if (do_tanh) {
        float a0 = ftanh(v.x), a1 = ftanh(v.y), a2 = ftanh(v.z), a3 = ftanh(v.w);
        *reinterpret_cast<ushort4*>(dst + (size_t)row * CDIM + tid * 4) =
            make_ushort4(f2bf(a0), f2bf(a1), f2bf(a2), f2bf(a3));
        float s = a0*a0 + a1*a1 + a2*a2 + a3*a3;
        #pragma unroll
        for (int m = 1; m < 64; m <<= 1) s += __shfl_xor(s, m, 64);
        if ((tid & 63) == 0) red[tid >> 6] = s;
        __syncthreads();
        if (tid == 0 && sq) sq[row] = red[0] + red[1] + red[2] + red[3];
    } else {
        *reinterpret_cast<ushort4*>(dst + (size_t)row * CDIM + tid * 4) =
            make_ushort4(f2bf(v.x), f2bf(v.y), f2bf(v.z), f2bf(v.w));
    }
}

// ---------------------------------------------------------------------------
// Fused QKV GEMM: C = A * Bm^T, distance epilogue; z = 0(q)/1(k)/2(v).
// 128x128 tile, BK=64, global_load_lds(16B), 4-bit XOR swizzle.
// k epilogue computes per-head row sq * C2 -> ksC2T.
__global__ __launch_bounds__(256) void gemm_qkv(const u16* __restrict__ xa,
                                                const u16* __restrict__ waq, const u16* __restrict__ wak, const u16* __restrict__ wav,
                                                u16* __restrict__ qb, u16* __restrict__ kb, u16* __restrict__ vT,
                                                const float* __restrict__ xsq,
                                                const float* __restrict__ sqq, const float* __restrict__ sqk, const float* __restrict__ sqv,
                                                const float* __restrict__ gq, const float* __restrict__ gk, const float* __restrict__ gv,
                                                float* __restrict__ ksC2T) {
    __shared__ __align__(16) u16 As[128 * 64];
    __shared__ __align__(16) u16 Bs[128 * 64];
    int z = blockIdx.z;
    const u16* Bm     = (z == 0) ? waq : (z == 1) ? wak : wav;
    const float* wsq  = (z == 0) ? sqq : (z == 1) ? sqk : sqv;
    const float* gain = (z == 0) ? gq : (z == 1) ? gk : gv;

    int tid = threadIdx.x;
    int m0 = blockIdx.y * 128, n0 = blockIdx.x * 128;
    int w = tid >> 6, l = tid & 63, wm = w >> 1, wn = w & 1, g = l >> 4, c = l & 15;
    int r8 = l >> 3, sl7 = l & 7;
    int cmask = (c & 7) ^ (c >> 3);

    floatx4 acc[4][4] = {};

    for (int kt = 0; kt < 16; ++kt) {
        __syncthreads();
        #pragma unroll
        for (int i = 0; i < 4; i++) {
            int ch = w * 4 + i;
            int row = ch * 8 + r8;
            int sl = sl7 ^ r8 ^ (ch & 1);
            gll16(xa + (size_t)(m0 + row) * CDIM + kt * 64 + sl * 8, &As[ch * 512 + l * 8]);
            gll16(Bm + (size_t)(n0 + row) * CDIM + kt * 64 + sl * 8, &Bs[ch * 512 + l * 8]);
        }
        __syncthreads();
        short8 af[2][4], bf[2][4];
        #pragma unroll
        for (int kk = 0; kk < 2; kk++) {
            #pragma unroll
            for (int mi = 0; mi < 4; mi++)
                af[kk][mi] = *reinterpret_cast<const short8*>(
                    &As[(wm * 64 + mi * 16 + c) * 64 + (((kk * 4 + g) ^ cmask) << 3)]);
            #pragma unroll
            for (int ni = 0; ni < 4; ni++)
                bf[kk][ni] = *reinterpret_cast<const short8*>(
                    &Bs[(wn * 64 + ni * 16 + c) * 64 + (((kk * 4 + g) ^ cmask) << 3)]);
        }
        #pragma unroll
        for (int kk = 0; kk < 2; kk++)
            #pragma unroll
            for (int mi = 0; mi < 4; mi++)
                #pragma unroll
                for (int ni = 0; ni < 4; ni++)
                    acc[mi][ni] = __builtin_amdgcn_mfma_f32_16x16x32_bf16(af[kk][mi], bf[kk][ni], acc[mi][ni], 0, 0, 0);
    }

    if (z < 2) {
        u16* outH = (z == 0) ? qb : kb;
        float part[4][4] = {};
        #pragma unroll
        for (int mi = 0; mi < 4; mi++) {
            int rowb = m0 + wm * 64 + mi * 16 + g * 4;
            #pragma unroll
            for (int ni = 0; ni < 4; ni++) {
                int col = n0 + wn * 64 + ni * 16 + c;
                float wsqc = wsq[col], gn = gain[col];
                #pragma unroll
                for (int r = 0; r < 4; r++) {
                    float l2 = fmaxf(xsq[rowb + r] + wsqc - 2.f * acc[mi][ni][r], 0.f);
                    float th = ftanh((0.5f - l2 * (1.f / 1024.f)) * gn);
                    outH[(size_t)(rowb + r) * CDIM + col] = f2bf(th);
                    part[mi][r] += th * th;
                }
            }
        }
        if (z == 1) {   // only k needs the per-head row-norm (pre-scaled by C2)
            int hh = blockIdx.x * 2 + wn;
            #pragma unroll
            for (int mi = 0; mi < 4; mi++)
                #pragma unroll
                for (int r = 0; r < 4; r++) {
                    float s = part[mi][r];
                    s += __shfl_xor(s, 1, 64); s += __shfl_xor(s, 2, 64);
                    s += __shfl_xor(s, 4, 64); s += __shfl_xor(s, 8, 64);
                    if (c == 0) {
                        int row = m0 + wm * 64 + mi * 16 + g * 4 + r;
                        int bb = row >> 11, t = row & 2047;
                        ksC2T[(size_t)(bb * NHEAD + hh) * TSEQ + t] = s * C2_CONST;
                    }
                }
        }
    } else {  // v: store transposed per head vT[b][h][d][t]
        #pragma unroll
        for (int mi = 0; mi < 4; mi++) {
            int rowb = m0 + wm * 64 + mi * 16 + g * 4;
            #pragma unroll
            for (int ni = 0; ni < 4; ni++) {
                int col = n0 + wn * 64 + ni * 16 + c;
                float wsqc = wsq[col], gn = gain[col];
                float vals[4];
                #pragma unroll
                for (int r = 0; r < 4; r++) {
                    float l2 = fmaxf(xsq[rowb + r] + wsqc - 2.f * acc[mi][ni][r], 0.f);
                    vals[r] = (0.5f - l2 * (1.f / 1024.f)) * gn;
                }
                int bb = rowb >> 11, t0 = rowb & 2047;
                int hh = col >> 6, dd = col & 63;
                ushort4 pv = make_ushort4(f2bf(vals[0]), f2bf(vals[1]), f2bf(vals[2]), f2bf(vals[3]));
                *reinterpret_cast<ushort4*>(&vT[(((size_t)(bb * NHEAD + hh) * HDIM + dd) << 11) + t0]) = pv;
            }
        }
    }
}

// ---------------------------------------------------------------------------
// Final GEMM: out = ao * Wo^T, f32 store.
__global__ __launch_bounds__(256) void gemm_out(const u16* __restrict__ A, const u16* __restrict__ Bm,
                                                float* __restrict__ outF) {
    __shared__ __align__(16) u16 As[128 * 64];
    __shared__ __align__(16) u16 Bs[128 * 64];
    int tid = threadIdx.x;
    int m0 = blockIdx.y * 128, n0 = blockIdx.x * 128;
    int w = tid >> 6, l = tid & 63, wm = w >> 1, wn = w & 1, g = l >> 4, c = l & 15;
    int r8 = l >> 3, sl7 = l & 7;
    int cmask = (c & 7) ^ (c >> 3);

    floatx4 acc[4][4] = {};

    for (int kt = 0; kt < 16; ++kt) {
        __syncthreads();
        #pragma unroll
        for (int i = 0; i < 4; i++) {
            int ch = w * 4 + i;
            int row = ch * 8 + r8;
            int sl = sl7 ^ r8 ^ (ch & 1);
            gll16(A + (size_t)(m0 + row) * CDIM + kt * 64 + sl * 8, &As[ch * 512 + l * 8]);
            gll16(Bm + (size_t)(n0 + row) * CDIM + kt * 64 + sl * 8, &Bs[ch * 512 + l * 8]);
        }
        __syncthreads();
        short8 af[2][4], bf[2][4];
        #pragma unroll
        for (int kk = 0; kk < 2; kk++) {
            #pragma unroll
            for (int mi = 0; mi < 4; mi++)
                af[kk][mi] = *reinterpret_cast<const short8*>(
                    &As[(wm * 64 + mi * 16 + c) * 64 + (((kk * 4 + g) ^ cmask) << 3)]);
            #pragma unroll
            for (int ni = 0; ni < 4; ni++)
                bf[kk][ni] = *reinterpret_cast<const short8*>(
                    &Bs[(wn * 64 + ni * 16 + c) * 64 + (((kk * 4 + g) ^ cmask) << 3)]);
        }
        #pragma unroll
        for (int kk = 0; kk < 2; kk++)
            #pragma unroll
            for (int mi = 0; mi < 4; mi++)
                #pragma unroll
                for (int ni = 0; ni < 4; ni++)
                    acc[mi][ni] = __builtin_amdgcn_mfma_f32_16x16x32_bf16(af[kk][mi], bf[kk][ni], acc[mi][ni], 0, 0, 0);
    }

    #pragma unroll
    for (int mi = 0; mi < 4; mi++) {
        int rowb = m0 + wm * 64 + mi * 16 + g * 4;
        #pragma unroll
        for (int ni = 0; ni < 4; ni++) {
            int col = n0 + wn * 64 + ni * 16 + c;
            #pragma unroll
            for (int r = 0; r < 4; r++)
                outF[(size_t)(rowb + r) * CDIM + col] = acc[mi][ni][r];
        }
    }
}

// ---------------------------------------------------------------------------
// attn6: 32x32x16 MFMA, swapped QK^T, fixed-m softmax. Per-STILE pipeline
// (QK^T -> softmax/pack -> exchange -> PV for each 32-s sub-tile) to cap
// register pressure; __launch_bounds__(256,2) sets VGPR budget to 256.
// grid (16, 16, 2) x 256; 4 waves x 32 q-rows; 32 s-tiles of 64.
__global__ __launch_bounds__(256, 2) void attn6(const u16* __restrict__ q, const u16* __restrict__ k,
                                                const u16* __restrict__ vT,
                                                const float* __restrict__ ksC2T, u16* __restrict__ ao) {
    int tt = blockIdx.x, h = blockIdx.y, b = blockIdx.z;
    int tid = threadIdx.x, w = tid >> 6, l = tid & 63;
    int hi = l >> 5, t32 = l & 31;
    int twb = tt * 128 + w * 32;

    __shared__ __align__(16) u16 Ks[2][64 * 64];   // [s][d-slots], XOR-swizzled
    __shared__ __align__(16) u16 Vs[2][64 * 64];   // [d][s-slots], XOR-swizzled
    __shared__ __align__(16) float Ls[4][32];

    // Q B-fragments: B[k=d][col=t], lane: Q[t=t32][d = ks*16 + hi*8 + j]
    short8 qf[4];
    size_t qrow = (size_t)(b * TSEQ + twb + t32) * CDIM + h * HDIM;
    #pragma unroll
    for (int ks = 0; ks < 4; ks++)
        qf[ks] = *reinterpret_cast<const short8*>(&q[qrow + ks * 16 + hi * 8]);

    const float* ksb = ksC2T + (size_t)(b * NHEAD + h) * TSEQ;
    const u16* kbase = k + (size_t)(b * TSEQ) * CDIM + h * HDIM;
    const u16* vbase = vT + (size_t)(b * NHEAD + h) * HDIM * TSEQ;

    int r8 = l >> 3, sl7 = l & 7;
    int lmask = (l & 7) ^ ((l >> 3) & 1);

    floatx16 oacc[2] = {};
    float lrun = 0.f;

    // prologue: stage tile 0
    #pragma unroll
    for (int i = 0; i < 2; i++) {
        int ch = w * 2 + i;
        int sl = sl7 ^ r8 ^ (ch & 1);
        gll16(kbase + (size_t)(ch * 8 + r8) * CDIM + sl * 8, &Ks[0][ch * 512 + l * 8]);
        gll16(vbase + (size_t)(ch * 8 + r8) * TSEQ + sl * 8, &Vs[0][ch * 512 + l * 8]);
    }
    __syncthreads();

    for (int st = 0; st < 32; ++st) {
        int cur = st & 1;
        if (st < 31) {
            int s1 = (st + 1) * 64;
            #pragma unroll
            for (int i = 0; i < 2; i++) {
                int ch = w * 2 + i;
                int sl = sl7 ^ r8 ^ (ch & 1);
                gll16(kbase + (size_t)(s1 + ch * 8 + r8) * CDIM + sl * 8, &Ks[cur ^ 1][ch * 512 + l * 8]);
                gll16(vbase + (size_t)(ch * 8 + r8) * TSEQ + s1 + sl * 8, &Vs[cur ^ 1][ch * 512 + l * 8]);
            }
        }

        // ---- per-stile pipeline: QK^T -> softmax/pack -> exchange -> PV
        #pragma unroll
        for (int stile = 0; stile < 2; ++stile) {
            // QK^T for this 32-s sub-tile
            floatx16 sxx = {};
            #pragma unroll
            for (int kstep = 0; kstep < 4; kstep++) {
                int row = stile * 32 + t32;
                int slot = (kstep * 2 + hi) ^ lmask;
                short8 kf = *reinterpret_cast<const short8*>(&Ks[cur][row * 64 + slot * 8]);
                sxx = __builtin_amdgcn_mfma_f32_32x32x16_bf16(kf, qf[kstep], sxx, 0, 0, 0);
            }

            // softmax (fixed m=0) + immediate bf16 pack
            u32 pk[8];
            #pragma unroll
            for (int qq = 0; qq < 4; qq++) {
                float4 kc = *reinterpret_cast<const float4*>(
                    &ksb[st * 64 + stile * 32 + qq * 8 + hi * 4]);
                float p0 = exp2f(fmaf(sxx[qq * 4 + 0], M2C2_CONST, kc.x));
                float p1 = exp2f(fmaf(sxx[qq * 4 + 1], M2C2_CONST, kc.y));
                float p2 = exp2f(fmaf(sxx[qq * 4 + 2], M2C2_CONST, kc.z));
                float p3 = exp2f(fmaf(sxx[qq * 4 + 3], M2C2_CONST, kc.w));
                lrun += (p0 + p1) + (p2 + p3);
                pk[qq * 2]     = cvtpk(p0, p1);
                pk[qq * 2 + 1] = cvtpk(p2, p3);
            }

            // cross-half exchange (each half sends what the other needs)
            u32 ex[4];
            #pragma unroll
            for (int m = 0; m < 4; m++) {
                const int p0a[4] = {0, 1, 4, 5};
                u32 send = hi ? pk[p0a[m]] : pk[p0a[m] + 2];
                ex[m] = (u32)__shfl_xor((int)send, 32, 64);
            }

            // PV for this stile's two k-steps
            #pragma unroll
            for (int e = 0; e < 2; e++) {
                int ks = stile * 2 + e;
                uint4v au;
                au.x = hi ? ex[2 * e]     : pk[4 * e];
                au.y = hi ? ex[2 * e + 1] : pk[4 * e + 1];
                au.z = hi ? pk[4 * e + 2] : ex[2 * e];
                au.w = hi ? pk[4 * e + 3] : ex[2 * e + 1];
                short8 af = __builtin_bit_cast(short8, au);
                #pragma unroll
                for (int dt = 0; dt < 2; dt++) {
                    int row = dt * 32 + t32;
                    int slot = (ks * 2 + hi) ^ lmask;
                    short8 vf = *reinterpret_cast<const short8*>(&Vs[cur][row * 64 + slot * 8]);
                    oacc[dt] = __builtin_amdgcn_mfma_f32_32x32x16_bf16(af, vf, oacc[dt], 0, 0, 0);
                }
            }
        }

        __syncthreads();   // all waves done with cur; next tile drained
    }

    // ---- epilogue: l broadcast (t-indexed -> row-indexed) + normalize
    float ltot = lrun + __shfl_xor(lrun, 32, 64);
    if (l < 32) Ls[w][l] = ltot;
    float4 lv[4];
    #pragma unroll
    for (int qq = 0; qq < 4; qq++)
        lv[qq] = *reinterpret_cast<const float4*>(&Ls[w][qq * 8 + hi * 4]);
    #pragma unroll
    for (int dt = 0; dt < 2; dt++)
        #pragma unroll
        for (int r = 0; r < 16; ++r) {
            int trow = (r & 3) + 8 * (r >> 2) + 4 * hi;
            float lval = (r & 3) == 0 ? lv[r >> 2].x : (r & 3) == 1 ? lv[r >> 2].y
                       : (r & 3) == 2 ? lv[r >> 2].z : lv[r >> 2].w;
            ao[(size_t)(b * TSEQ + twb + trow) * CDIM + h * HDIM + dt * 32 + t32] =
                f2bf(oacc[dt][r] * __builtin_amdgcn_rcpf(lval));
        }
}

// ---------------------------------------------------------------------------
extern "C" void kernel_launch(void* const* d_in, const int* in_sizes, int n_in,
                              void* d_out, int out_size, void* d_ws, size_t ws_size,
                              hipStream_t stream) {
    const float* x  = (const float*)d_in[0];
    const float* Wq = (const float*)d_in[1];
    const float* gq = (const float*)d_in[2];
    const float* Wk = (const float*)d_in[3];
    const float* gk = (const float*)d_in[4];
    const float* Wv = (const float*)d_in[5];
    const float* gv = (const float*)d_in[6];
    const float* Wo = (const float*)d_in[7];
    float* out = (float*)d_out;

    char* p = (char*)d_ws;
    u16* xa  = (u16*)p;  p += (size_t)8 << 20;
    u16* qb  = (u16*)p;  p += (size_t)8 << 20;
    u16* kb  = (u16*)p;  p += (size_t)8 << 20;
    u16* vT  = (u16*)p;  p += (size_t)8 << 20;
    u16* ao  = (u16*)p;  p += (size_t)8 << 20;
    u16* waq = (u16*)p;  p += (size_t)2 << 20;
    u16* wak = (u16*)p;  p += (size_t)2 << 20;
    u16* wav = (u16*)p;  p += (size_t)2 << 20;
    u16* wob = (u16*)p;  p += (size_t)2 << 20;
    float* xsq   = (float*)p; p += 4096 * 4;
    float* sqq   = (float*)p; p += 1024 * 4;
    float* sqk   = (float*)p; p += 1024 * 4;
    float* sqv   = (float*)p; p += 1024 * 4;
    float* ksC2T = (float*)p; p += 4096 * 16 * 4;
    (void)ws_size; (void)in_sizes; (void)n_in; (void)out_size;

    prep<<<8192, 256, 0, stream>>>(x, Wq, Wk, Wv, Wo, xa, waq, wak, wav, wob,
                                   xsq, sqq, sqk, sqv);

    dim3 gqkv(8, 32, 3);
    gemm_qkv<<<gqkv, 256, 0, stream>>>(xa, waq, wak, wav, qb, kb, vT, xsq,
                                       sqq, sqk, sqv, gq, gk, gv, ksC2T);

    dim3 ga(16, NHEAD, 2);
    attn6<<<ga, 256, 0, stream>>>(qb, kb, vT, ksC2T, ao);

    dim3 gg(8, 32);
    gemm_out<<<gg, 256, 0, stream>>>(ao, wob, out);
}

// Round 7
// 140.434 us; speedup vs baseline: 1.5079x; 1.1561x over previous
//
#include <hip/hip_runtime.h>
#include <hip/hip_bf16.h>
#include <math.h>

typedef unsigned short u16;
typedef unsigned int u32;
typedef __attribute__((ext_vector_type(8))) short short8;
typedef __attribute__((ext_vector_type(8))) unsigned short ushort8;
typedef __attribute__((ext_vector_type(4))) float floatx4;
typedef __attribute__((ext_vector_type(16))) float floatx16;
typedef __attribute__((ext_vector_type(4))) u32 uint4v;

#define CDIM   1024
#define TSEQ   2048
#define NHEAD  16
#define HDIM   64

// -1/(80*ln2): exp(-dist/80) = exp2(dist * C2)
#define C2_CONST  (-0.01803368801111874f)
#define M2C2_CONST (0.03606737602223748f)

static __device__ __forceinline__ u16 f2bf(float f) {
    u32 u = __float_as_uint(f);
    u += 0x7fffu + ((u >> 16) & 1u);   // RNE
    return (u16)(u >> 16);
}

// packed f32x2 -> bf16x2 (RNE), single VOP3
static __device__ __forceinline__ u32 cvtpk(float a, float b) {
    u32 r;
    asm("v_cvt_pk_bf16_f32 %0, %1, %2" : "=v"(r) : "v"(a), "v"(b));
    return r;
}

// fast tanh: 1 - 2/(exp2(2x*log2e)+1)
static __device__ __forceinline__ float ftanh(float x) {
    float e = exp2f(x * 2.88539008f);
    float r = __builtin_amdgcn_rcpf(e + 1.0f);
    return fmaf(-2.0f, r, 1.0f);
}

// async global->LDS, 16 bytes per lane
static __device__ __forceinline__ void gll16(const void* g, void* l) {
    __builtin_amdgcn_global_load_lds(
        (const __attribute__((address_space(1))) unsigned int*)g,
        (__attribute__((address_space(3))) unsigned int*)l, 16, 0, 0);
}

// ---------------------------------------------------------------------------
// prep: bid<4096 -> xa=tanh(x)+xsq ; else W mats (tanh+wsq for q/k/v, copy Wo)
__global__ __launch_bounds__(256) void prep(const float* __restrict__ x,
                                            const float* __restrict__ Wq, const float* __restrict__ Wk,
                                            const float* __restrict__ Wv, const float* __restrict__ Wo,
                                            u16* __restrict__ xa,
                                            u16* __restrict__ waq, u16* __restrict__ wak,
                                            u16* __restrict__ wav, u16* __restrict__ wob,
                                            float* __restrict__ xsq,
                                            float* __restrict__ sqq, float* __restrict__ sqk,
                                            float* __restrict__ sqv) {
    __shared__ float red[4];
    int bid = blockIdx.x, tid = threadIdx.x;
    const float* src; u16* dst; float* sq; int row; bool do_tanh = true;
    if (bid < 4096) {
        row = bid; src = x; dst = xa; sq = xsq;
    } else {
        int mat = (bid - 4096) >> 10; row = (bid - 4096) & 1023;
        src = (mat == 0) ? Wq : (mat == 1) ? Wk : (mat == 2) ? Wv : Wo;
        dst = (mat == 0) ? waq : (mat == 1) ? wak : (mat == 2) ? wav : wob;
        sq  = (mat == 0) ? sqq : (mat == 1) ? sqk : (mat == 2) ? sqv : nullptr;
        do_tanh = (mat < 3);
    }
    float4 v = reinterpret_cast<const float4*>(src + (size_t)row * CDIM)[tid];
    if (do_tanh) {
        float a0 = ftanh(v.x), a1 = ftanh(v.y), a2 = ftanh(v.z), a3 = ftanh(v.w);
        *reinterpret_cast<ushort4*>(dst + (size_t)row * CDIM + tid * 4) =
            make_ushort4(f2bf(a0), f2bf(a1), f2bf(a2), f2bf(a3));
        float s = a0*a0 + a1*a1 + a2*a2 + a3*a3;
        #pragma unroll
        for (int m = 1; m < 64; m <<= 1) s += __shfl_xor(s, m, 64);
        if ((tid & 63) == 0) red[tid >> 6] = s;
        __syncthreads();
        if (tid == 0 && sq) sq[row] = red[0] + red[1] + red[2] + red[3];
    } else {
        *reinterpret_cast<ushort4*>(dst + (size_t)row * CDIM + tid * 4) =
            make_ushort4(f2bf(v.x), f2bf(v.y), f2bf(v.z), f2bf(v.w));
    }
}

// ---------------------------------------------------------------------------
// Fused QKV GEMM: C = A * Bm^T, distance epilogue; z = 0(q)/1(k)/2(v).
// Outputs are written in MFMA-FRAGMENT layout for attn7's direct global->reg
// loads:
//   q/k frag: [hb][tile32][kstep0..3][lane(hi*32+l31)][j]  (lane&31 = t/s row,
//             d = kstep*16 + (lane>>5)*8 + j)
//   v frag:   [hb][dt0..1][tile32][e0..1][lane(hi8*32+d31)][j]
//             (value V[s][dt*32+d31], s = tile*32 + e*16 + hi8*8 + j)
// k epilogue also computes per-head row sq * C2 -> ksC2T.
__global__ __launch_bounds__(256) void gemm_qkv(const u16* __restrict__ xa,
                                                const u16* __restrict__ waq, const u16* __restrict__ wak, const u16* __restrict__ wav,
                                                u16* __restrict__ qF, u16* __restrict__ kF, u16* __restrict__ vF,
                                                const float* __restrict__ xsq,
                                                const float* __restrict__ sqq, const float* __restrict__ sqk, const float* __restrict__ sqv,
                                                const float* __restrict__ gq, const float* __restrict__ gk, const float* __restrict__ gv,
                                                float* __restrict__ ksC2T) {
    __shared__ __align__(16) u16 As[128 * 64];
    __shared__ __align__(16) u16 Bs[128 * 64];
    int z = blockIdx.z;
    const u16* Bm     = (z == 0) ? waq : (z == 1) ? wak : wav;
    const float* wsq  = (z == 0) ? sqq : (z == 1) ? sqk : sqv;
    const float* gain = (z == 0) ? gq : (z == 1) ? gk : gv;

    int tid = threadIdx.x;
    int m0 = blockIdx.y * 128, n0 = blockIdx.x * 128;
    int w = tid >> 6, l = tid & 63, wm = w >> 1, wn = w & 1, g = l >> 4, c = l & 15;
    int r8 = l >> 3, sl7 = l & 7;
    int cmask = (c & 7) ^ (c >> 3);

    floatx4 acc[4][4] = {};

    for (int kt = 0; kt < 16; ++kt) {
        __syncthreads();
        #pragma unroll
        for (int i = 0; i < 4; i++) {
            int ch = w * 4 + i;
            int row = ch * 8 + r8;
            int sl = sl7 ^ r8 ^ (ch & 1);
            gll16(xa + (size_t)(m0 + row) * CDIM + kt * 64 + sl * 8, &As[ch * 512 + l * 8]);
            gll16(Bm + (size_t)(n0 + row) * CDIM + kt * 64 + sl * 8, &Bs[ch * 512 + l * 8]);
        }
        __syncthreads();
        short8 af[2][4], bf[2][4];
        #pragma unroll
        for (int kk = 0; kk < 2; kk++) {
            #pragma unroll
            for (int mi = 0; mi < 4; mi++)
                af[kk][mi] = *reinterpret_cast<const short8*>(
                    &As[(wm * 64 + mi * 16 + c) * 64 + (((kk * 4 + g) ^ cmask) << 3)]);
            #pragma unroll
            for (int ni = 0; ni < 4; ni++)
                bf[kk][ni] = *reinterpret_cast<const short8*>(
                    &Bs[(wn * 64 + ni * 16 + c) * 64 + (((kk * 4 + g) ^ cmask) << 3)]);
        }
        #pragma unroll
        for (int kk = 0; kk < 2; kk++)
            #pragma unroll
            for (int mi = 0; mi < 4; mi++)
                #pragma unroll
                for (int ni = 0; ni < 4; ni++)
                    acc[mi][ni] = __builtin_amdgcn_mfma_f32_16x16x32_bf16(af[kk][mi], bf[kk][ni], acc[mi][ni], 0, 0, 0);
    }

    if (z < 2) {
        u16* outF = (z == 0) ? qF : kF;
        float part[4][4] = {};
        #pragma unroll
        for (int mi = 0; mi < 4; mi++) {
            int rowb = m0 + wm * 64 + mi * 16 + g * 4;
            int bb = rowb >> 11, tt = rowb & 2047;
            int tile = tt >> 5, l31 = tt & 31;
            #pragma unroll
            for (int ni = 0; ni < 4; ni++) {
                int col = n0 + wn * 64 + ni * 16 + c;
                int hh = col >> 6, d = col & 63;
                int kst = d >> 4, hi8 = (d >> 3) & 1, j = d & 7;
                size_t base = ((((size_t)(bb * NHEAD + hh) * 64 + tile) * 4 + kst) * 2 + hi8) * 256 + j;
                float wsqc = wsq[col], gn = gain[col];
                #pragma unroll
                for (int r = 0; r < 4; r++) {
                    float l2 = fmaxf(xsq[rowb + r] + wsqc - 2.f * acc[mi][ni][r], 0.f);
                    float th = ftanh((0.5f - l2 * (1.f / 1024.f)) * gn);
                    outF[base + (size_t)(l31 + r) * 8] = f2bf(th);
                    part[mi][r] += th * th;
                }
            }
        }
        if (z == 1) {   // only k needs the per-head row-norm (pre-scaled by C2)
            int hh = blockIdx.x * 2 + wn;
            #pragma unroll
            for (int mi = 0; mi < 4; mi++)
                #pragma unroll
                for (int r = 0; r < 4; r++) {
                    float s = part[mi][r];
                    s += __shfl_xor(s, 1, 64); s += __shfl_xor(s, 2, 64);
                    s += __shfl_xor(s, 4, 64); s += __shfl_xor(s, 8, 64);
                    if (c == 0) {
                        int row = m0 + wm * 64 + mi * 16 + g * 4 + r;
                        int bb = row >> 11, t = row & 2047;
                        ksC2T[(size_t)(bb * NHEAD + hh) * TSEQ + t] = s * C2_CONST;
                    }
                }
        }
    } else {  // v: store in PV B-fragment layout
        #pragma unroll
        for (int mi = 0; mi < 4; mi++) {
            int rowb = m0 + wm * 64 + mi * 16 + g * 4;
            int bb = rowb >> 11, s = rowb & 2047;
            int tile = s >> 5, e = (s >> 4) & 1, hi8 = (s >> 3) & 1, j0 = s & 7;
            #pragma unroll
            for (int ni = 0; ni < 4; ni++) {
                int col = n0 + wn * 64 + ni * 16 + c;
                int hh = col >> 6, d = col & 63;
                int dt = d >> 5, l31 = d & 31;
                float wsqc = wsq[col], gn = gain[col];
                float vals[4];
                #pragma unroll
                for (int r = 0; r < 4; r++) {
                    float l2 = fmaxf(xsq[rowb + r] + wsqc - 2.f * acc[mi][ni][r], 0.f);
                    vals[r] = (0.5f - l2 * (1.f / 1024.f)) * gn;
                }
                size_t idx = (((((size_t)(bb * NHEAD + hh) * 2 + dt) * 64 + tile) * 2 + e) * 2 + hi8) * 256
                             + (size_t)l31 * 8 + j0;
                *reinterpret_cast<ushort4*>(&vF[idx]) =
                    make_ushort4(f2bf(vals[0]), f2bf(vals[1]), f2bf(vals[2]), f2bf(vals[3]));
            }
        }
    }
}

// ---------------------------------------------------------------------------
// Final GEMM: out = ao * Wo^T, f32 store.
__global__ __launch_bounds__(256) void gemm_out(const u16* __restrict__ A, const u16* __restrict__ Bm,
                                                float* __restrict__ outF) {
    __shared__ __align__(16) u16 As[128 * 64];
    __shared__ __align__(16) u16 Bs[128 * 64];
    int tid = threadIdx.x;
    int m0 = blockIdx.y * 128, n0 = blockIdx.x * 128;
    int w = tid >> 6, l = tid & 63, wm = w >> 1, wn = w & 1, g = l >> 4, c = l & 15;
    int r8 = l >> 3, sl7 = l & 7;
    int cmask = (c & 7) ^ (c >> 3);

    floatx4 acc[4][4] = {};

    for (int kt = 0; kt < 16; ++kt) {
        __syncthreads();
        #pragma unroll
        for (int i = 0; i < 4; i++) {
            int ch = w * 4 + i;
            int row = ch * 8 + r8;
            int sl = sl7 ^ r8 ^ (ch & 1);
            gll16(A + (size_t)(m0 + row) * CDIM + kt * 64 + sl * 8, &As[ch * 512 + l * 8]);
            gll16(Bm + (size_t)(n0 + row) * CDIM + kt * 64 + sl * 8, &Bs[ch * 512 + l * 8]);
        }
        __syncthreads();
        short8 af[2][4], bf[2][4];
        #pragma unroll
        for (int kk = 0; kk < 2; kk++) {
            #pragma unroll
            for (int mi = 0; mi < 4; mi++)
                af[kk][mi] = *reinterpret_cast<const short8*>(
                    &As[(wm * 64 + mi * 16 + c) * 64 + (((kk * 4 + g) ^ cmask) << 3)]);
            #pragma unroll
            for (int ni = 0; ni < 4; ni++)
                bf[kk][ni] = *reinterpret_cast<const short8*>(
                    &Bs[(wn * 64 + ni * 16 + c) * 64 + (((kk * 4 + g) ^ cmask) << 3)]);
        }
        #pragma unroll
        for (int kk = 0; kk < 2; kk++)
            #pragma unroll
            for (int mi = 0; mi < 4; mi++)
                #pragma unroll
                for (int ni = 0; ni < 4; ni++)
                    acc[mi][ni] = __builtin_amdgcn_mfma_f32_16x16x32_bf16(af[kk][mi], bf[kk][ni], acc[mi][ni], 0, 0, 0);
    }

    #pragma unroll
    for (int mi = 0; mi < 4; mi++) {
        int rowb = m0 + wm * 64 + mi * 16 + g * 4;
        #pragma unroll
        for (int ni = 0; ni < 4; ni++) {
            int col = n0 + wn * 64 + ni * 16 + c;
            #pragma unroll
            for (int r = 0; r < 4; r++)
                outF[(size_t)(rowb + r) * CDIM + col] = acc[mi][ni][r];
        }
    }
}

// ---------------------------------------------------------------------------
// attn7: LDS-free main loop. Q/K/V pre-laid-out in MFMA fragment order ->
// direct coalesced global->reg loads, zero barriers per tile. Fixed-m softmax
// partials are additive: 4 waves = 2 q-groups x 2 s-chunks; one LDS combine
// at the end. grid 1024 (32 ttiles x 32 hb, hb%8 = XCD for L2 locality).
__global__ __launch_bounds__(256, 4) void attn7(const u16* __restrict__ qF, const u16* __restrict__ kF,
                                                const u16* __restrict__ vF,
                                                const float* __restrict__ ksC2T, u16* __restrict__ ao) {
    int bid = blockIdx.x;
    int hb = bid & 31;                 // b*16+h; all 32 t-blocks of an hb share an XCD
    int ttile = bid >> 5;              // 0..31 (64 q-rows each)
    int tid = threadIdx.x, w = tid >> 6, l = tid & 63;
    int qg = w >> 1, sc = w & 1;
    int hi = l >> 5, t32 = l & 31;

    __shared__ float redO[2][64][33];
    __shared__ float Ls[2][32];

    // Q B-fragments (loaded once, coalesced)
    const u16* qbase = qF + ((size_t)hb * 64 + ttile * 2 + qg) * 2048;
    short8 qf[4];
    #pragma unroll
    for (int ks = 0; ks < 4; ks++)
        qf[ks] = *reinterpret_cast<const short8*>(qbase + ks * 512 + (size_t)l * 8);

    const u16* kbase = kF + (size_t)hb * (64 * 2048);
    const u16* vbase = vF + (size_t)hb * (2 * 64 * 1024);
    const float* ksb = ksC2T + (size_t)hb * TSEQ;

    floatx16 oacc[2] = {};
    float lrun = 0.f;

    int st0 = sc * 32;
    for (int st = st0; st < st0 + 32; ++st) {
        // K A-fragments: 4 coalesced 1KB loads
        const short8* kp = reinterpret_cast<const short8*>(kbase + (size_t)st * 2048) + l;
        short8 kf0 = kp[0], kf1 = kp[64], kf2 = kp[128], kf3 = kp[192];
        // V B-fragments (issued early; used after softmax)
        const short8* vp = reinterpret_cast<const short8*>(vbase + (size_t)st * 1024) + l;
        short8 vf00 = vp[0], vf01 = vp[64];        // dt=0, e=0/1
        short8 vf10 = vp[8192], vf11 = vp[8256];   // dt=1, e=0/1

        // ---- S^T = K.Q^T (lane: col t = t32, 16 s-rows in regs)
        floatx16 sxx = {};
        sxx = __builtin_amdgcn_mfma_f32_32x32x16_bf16(kf0, qf[0], sxx, 0, 0, 0);
        sxx = __builtin_amdgcn_mfma_f32_32x32x16_bf16(kf1, qf[1], sxx, 0, 0, 0);
        sxx = __builtin_amdgcn_mfma_f32_32x32x16_bf16(kf2, qf[2], sxx, 0, 0, 0);
        sxx = __builtin_amdgcn_mfma_f32_32x32x16_bf16(kf3, qf[3], sxx, 0, 0, 0);

        // ---- fixed-m softmax + bf16 pack
        u32 pk[8];
        #pragma unroll
        for (int qq = 0; qq < 4; qq++) {
            float4 kc = *reinterpret_cast<const float4*>(&ksb[st * 32 + qq * 8 + hi * 4]);
            float p0 = exp2f(fmaf(sxx[qq * 4 + 0], M2C2_CONST, kc.x));
            float p1 = exp2f(fmaf(sxx[qq * 4 + 1], M2C2_CONST, kc.y));
            float p2 = exp2f(fmaf(sxx[qq * 4 + 2], M2C2_CONST, kc.z));
            float p3 = exp2f(fmaf(sxx[qq * 4 + 3], M2C2_CONST, kc.w));
            lrun += (p0 + p1) + (p2 + p3);
            pk[qq * 2]     = cvtpk(p0, p1);
            pk[qq * 2 + 1] = cvtpk(p2, p3);
        }

        // ---- cross-half exchange
        u32 ex[4];
        #pragma unroll
        for (int m = 0; m < 4; m++) {
            const int p0a[4] = {0, 1, 4, 5};
            u32 send = hi ? pk[p0a[m]] : pk[p0a[m] + 2];
            ex[m] = (u32)__shfl_xor((int)send, 32, 64);
        }

        // ---- O += P.V
        #pragma unroll
        for (int e = 0; e < 2; e++) {
            uint4v au;
            au.x = hi ? ex[2 * e]     : pk[4 * e];
            au.y = hi ? ex[2 * e + 1] : pk[4 * e + 1];
            au.z = hi ? pk[4 * e + 2] : ex[2 * e];
            au.w = hi ? pk[4 * e + 3] : ex[2 * e + 1];
            short8 af = __builtin_bit_cast(short8, au);
            oacc[0] = __builtin_amdgcn_mfma_f32_32x32x16_bf16(af, e ? vf01 : vf00, oacc[0], 0, 0, 0);
            oacc[1] = __builtin_amdgcn_mfma_f32_32x32x16_bf16(af, e ? vf11 : vf10, oacc[1], 0, 0, 0);
        }
    }

    // ---- combine s-chunks (fixed-m: partials just add), then normalize+store
    if (sc == 1) {
        #pragma unroll
        for (int dt = 0; dt < 2; dt++)
            #pragma unroll
            for (int r = 0; r < 16; r++)
                redO[qg][l][dt * 16 + r] = oacc[dt][r];
        redO[qg][l][32] = lrun;
    }
    __syncthreads();
    if (sc == 0) {
        #pragma unroll
        for (int dt = 0; dt < 2; dt++)
            #pragma unroll
            for (int r = 0; r < 16; r++)
                oacc[dt][r] += redO[qg][l][dt * 16 + r];
        lrun += redO[qg][l][32];
        float ltot = lrun + __shfl_xor(lrun, 32, 64);
        if (l < 32) Ls[qg][l] = ltot;
        int b = hb >> 4, h = hb & 15;
        int twb = ttile * 64 + qg * 32;
        float4 lv[4];
        #pragma unroll
        for (int qq = 0; qq < 4; qq++)
            lv[qq] = *reinterpret_cast<const float4*>(&Ls[qg][qq * 8 + hi * 4]);
        #pragma unroll
        for (int dt = 0; dt < 2; dt++)
            #pragma unroll
            for (int r = 0; r < 16; ++r) {
                int trow = (r & 3) + 8 * (r >> 2) + 4 * hi;
                float lval = (r & 3) == 0 ? lv[r >> 2].x : (r & 3) == 1 ? lv[r >> 2].y
                           : (r & 3) == 2 ? lv[r >> 2].z : lv[r >> 2].w;
                ao[(size_t)(b * TSEQ + twb + trow) * CDIM + h * HDIM + dt * 32 + t32] =
                    f2bf(oacc[dt][r] * __builtin_amdgcn_rcpf(lval));
            }
    }
}

// ---------------------------------------------------------------------------
extern "C" void kernel_launch(void* const* d_in, const int* in_sizes, int n_in,
                              void* d_out, int out_size, void* d_ws, size_t ws_size,
                              hipStream_t stream) {
    const float* x  = (const float*)d_in[0];
    const float* Wq = (const float*)d_in[1];
    const float* gq = (const float*)d_in[2];
    const float* Wk = (const float*)d_in[3];
    const float* gk = (const float*)d_in[4];
    const float* Wv = (const float*)d_in[5];
    const float* gv = (const float*)d_in[6];
    const float* Wo = (const float*)d_in[7];
    float* out = (float*)d_out;

    char* p = (char*)d_ws;
    u16* xa  = (u16*)p;  p += (size_t)8 << 20;
    u16* qF  = (u16*)p;  p += (size_t)8 << 20;
    u16* kF  = (u16*)p;  p += (size_t)8 << 20;
    u16* vF  = (u16*)p;  p += (size_t)8 << 20;
    u16* ao  = (u16*)p;  p += (size_t)8 << 20;
    u16* waq = (u16*)p;  p += (size_t)2 << 20;
    u16* wak = (u16*)p;  p += (size_t)2 << 20;
    u16* wav = (u16*)p;  p += (size_t)2 << 20;
    u16* wob = (u16*)p;  p += (size_t)2 << 20;
    float* xsq   = (float*)p; p += 4096 * 4;
    float* sqq   = (float*)p; p += 1024 * 4;
    float* sqk   = (float*)p; p += 1024 * 4;
    float* sqv   = (float*)p; p += 1024 * 4;
    float* ksC2T = (float*)p; p += 4096 * 16 * 4;
    (void)ws_size; (void)in_sizes; (void)n_in; (void)out_size;

    prep<<<8192, 256, 0, stream>>>(x, Wq, Wk, Wv, Wo, xa, waq, wak, wav, wob,
                                   xsq, sqq, sqk, sqv);

    dim3 gqkv(8, 32, 3);
    gemm_qkv<<<gqkv, 256, 0, stream>>>(xa, waq, wak, wav, qF, kF, vF, xsq,
                                       sqq, sqk, sqv, gq, gk, gv, ksC2T);

    attn7<<<1024, 256, 0, stream>>>(qF, kF, vF, ksC2T, ao);

    dim3 gg(8, 32);
    gemm_out<<<gg, 256, 0, stream>>>(ao, wob, out);
}